// Round 5
// baseline (886.506 us; speedup 1.0000x reference)
//
#include <hip/hip_runtime.h>
#include <hip/hip_fp8.h>

#define T_SEQ 769
#define N_SENT 768
#define E_IN 256
#define HID 128
#define G4 512
#define F_DIM 128

typedef float f32x4 __attribute__((ext_vector_type(4)));
typedef int i32x8 __attribute__((ext_vector_type(8)));

#if __has_builtin(__builtin_amdgcn_rcpf)
#define RCPF(x) __builtin_amdgcn_rcpf(x)
#else
#define RCPF(x) (1.0f / (x))
#endif

#if __has_builtin(__builtin_amdgcn_exp2f)
#define EXP2F(x) __builtin_amdgcn_exp2f(x)
#else
#define EXP2F(x) __builtin_exp2f(x)
#endif

// LDS-only barrier: waits lgkmcnt(0) then s_barrier; global prefetch loads
// stay in flight (vmcnt not drained).
#define LDS_BARRIER() asm volatile("s_waitcnt lgkmcnt(0)\n\ts_barrier" ::: "memory")

#define L2E 1.4426950408889634f

__device__ __forceinline__ float tanh_fast(float x) {
    return fmaf(2.0f, RCPF(1.0f + EXP2F(-2.0f * L2E * x)), -1.0f);
}

// h -> e4m3 byte via the HW packed convert (single VALU op on gfx950).
__device__ __forceinline__ unsigned char f32_to_e4m3(float x) {
#if __has_builtin(__builtin_amdgcn_cvt_pk_fp8_f32)
    return (unsigned char)(__builtin_amdgcn_cvt_pk_fp8_f32(x, x, 0, false) & 0xFF);
#else
    __hip_fp8_e4m3 q(x);
    return (unsigned char)q.__x;
#endif
}

// pack 4 floats -> 4 e4m3 bytes in one dword (2 HW instructions)
__device__ __forceinline__ int pack4_e4m3(float w0, float w1, float w2, float w3) {
#if __has_builtin(__builtin_amdgcn_cvt_pk_fp8_f32)
    int r = __builtin_amdgcn_cvt_pk_fp8_f32(w0, w1, 0, false);   // bits 15:0
    return __builtin_amdgcn_cvt_pk_fp8_f32(w2, w3, r, true);     // bits 31:16
#else
    unsigned x = 0;
    __hip_fp8_e4m3 q0(w0), q1(w1), q2(w2), q3(w3);
    x |= (unsigned)q0.__x;
    x |= (unsigned)q1.__x << 8;
    x |= (unsigned)q2.__x << 16;
    x |= (unsigned)q3.__x << 24;
    return (int)x;
#endif
}

// quad-lane broadcast via DPP (lanes [4k..4k+3] all get lane 4k+sel)
__device__ __forceinline__ float quad_bcast(float x, const int sel) {
#if __has_builtin(__builtin_amdgcn_mov_dpp)
    // quad_perm: all four 2-bit selects = sel -> 0x00 / 0x55 / 0xAA / 0xFF
    int ctrl = sel * 0x55;
    int r;
    switch (ctrl) {
        case 0x00: r = __builtin_amdgcn_mov_dpp(__float_as_int(x), 0x00, 0xF, 0xF, true); break;
        case 0x55: r = __builtin_amdgcn_mov_dpp(__float_as_int(x), 0x55, 0xF, 0xF, true); break;
        case 0xAA: r = __builtin_amdgcn_mov_dpp(__float_as_int(x), 0xAA, 0xF, 0xF, true); break;
        default:   r = __builtin_amdgcn_mov_dpp(__float_as_int(x), 0xFF, 0xF, 0xF, true); break;
    }
    return __int_as_float(r);
#else
    int lane = __lane_id();
    return __shfl(x, (lane & ~3) + sel, 64);
#endif
}

// ---------------- pre-GEMM, layer 0 (x built inline from sent/root) --------
__global__ __launch_bounds__(256) void pre_gemm_l0(
    const float* __restrict__ sent, const float* __restrict__ root,
    const float* __restrict__ Wih, const float* __restrict__ bih,
    const float* __restrict__ bhh, float* __restrict__ pre)
{
    const int d = blockIdx.z;
    const float* B = Wih + (size_t)d * G4 * E_IN;
    const float* b0 = bih + (size_t)d * G4;
    const float* b1 = bhh + (size_t)d * G4;
    float* C = pre + (size_t)d * T_SEQ * G4;

    __shared__ __align__(16) float As[16][68];
    __shared__ __align__(16) float Bs[16][68];
    int tid = threadIdx.x;
    int tx = tid & 15, ty = tid >> 4;
    int m0 = blockIdx.x * 64, n0 = blockIdx.y * 64;
    float acc[4][4] = {};
    int lrow = tid >> 2;
    int lk = (tid & 3) << 2;

    for (int k0 = 0; k0 < E_IN; k0 += 16) {
        int m = m0 + lrow;
        float4 av = make_float4(0.f, 0.f, 0.f, 0.f);
        if (m < T_SEQ) {
            int ar = d ? (N_SENT - m) : m;
            av = (ar < N_SENT)
                     ? *(const float4*)(sent + (size_t)ar * E_IN + k0 + lk)
                     : *(const float4*)(root + k0 + lk);
        }
        As[lk + 0][lrow] = av.x; As[lk + 1][lrow] = av.y;
        As[lk + 2][lrow] = av.z; As[lk + 3][lrow] = av.w;
        float4 bv = *(const float4*)(B + (size_t)(n0 + lrow) * E_IN + k0 + lk);
        Bs[lk + 0][lrow] = bv.x; Bs[lk + 1][lrow] = bv.y;
        Bs[lk + 2][lrow] = bv.z; Bs[lk + 3][lrow] = bv.w;
        __syncthreads();
        #pragma unroll
        for (int k = 0; k < 16; ++k) {
            float4 a4 = *(const float4*)&As[k][ty * 4];
            float4 b4 = *(const float4*)&Bs[k][tx * 4];
            float aa[4] = {a4.x, a4.y, a4.z, a4.w};
            float bb[4] = {b4.x, b4.y, b4.z, b4.w};
            #pragma unroll
            for (int i = 0; i < 4; ++i)
                #pragma unroll
                for (int j = 0; j < 4; ++j)
                    acc[i][j] = fmaf(aa[i], bb[j], acc[i][j]);
        }
        __syncthreads();
    }
    float bias[4];
    #pragma unroll
    for (int j = 0; j < 4; ++j) {
        int n = n0 + tx * 4 + j;
        bias[j] = b0[n] + b1[n];
    }
    #pragma unroll
    for (int i = 0; i < 4; ++i) {
        int m = m0 + ty * 4 + i;
        if (m < T_SEQ) {
            #pragma unroll
            for (int j = 0; j < 4; ++j)
                C[(size_t)m * G4 + n0 + tx * 4 + j] = acc[i][j] + bias[j];
        }
    }
}

// ---------------- pre-GEMM, layer 1 ---------------------------------------
__global__ __launch_bounds__(256) void pre_gemm_l1(
    const float* __restrict__ L0,
    const float* __restrict__ Wih, const float* __restrict__ bih,
    const float* __restrict__ bhh, float* __restrict__ pre)
{
    const int d = blockIdx.z;
    const float* B = Wih + (size_t)(2 + d) * G4 * E_IN;
    const float* b0 = bih + (size_t)(2 + d) * G4;
    const float* b1 = bhh + (size_t)(2 + d) * G4;
    float* C = pre + (size_t)d * T_SEQ * G4;

    __shared__ __align__(16) float As[16][68];
    __shared__ __align__(16) float Bs[16][68];
    int tid = threadIdx.x;
    int tx = tid & 15, ty = tid >> 4;
    int m0 = blockIdx.x * 64, n0 = blockIdx.y * 64;
    float acc[4][4] = {};
    int lrow = tid >> 2;
    int lk = (tid & 3) << 2;

    for (int k0 = 0; k0 < 256; k0 += 16) {
        int m = m0 + lrow;
        float4 av = make_float4(0.f, 0.f, 0.f, 0.f);
        if (m < T_SEQ) {
            int ar = d ? (N_SENT - m) : m;
            av = *(const float4*)(L0 + (size_t)ar * 256 + k0 + lk);
        }
        As[lk + 0][lrow] = av.x; As[lk + 1][lrow] = av.y;
        As[lk + 2][lrow] = av.z; As[lk + 3][lrow] = av.w;
        float4 bv = *(const float4*)(B + (size_t)(n0 + lrow) * 256 + k0 + lk);
        Bs[lk + 0][lrow] = bv.x; Bs[lk + 1][lrow] = bv.y;
        Bs[lk + 2][lrow] = bv.z; Bs[lk + 3][lrow] = bv.w;
        __syncthreads();
        #pragma unroll
        for (int k = 0; k < 16; ++k) {
            float4 a4 = *(const float4*)&As[k][ty * 4];
            float4 b4 = *(const float4*)&Bs[k][tx * 4];
            float aa[4] = {a4.x, a4.y, a4.z, a4.w};
            float bb[4] = {b4.x, b4.y, b4.z, b4.w};
            #pragma unroll
            for (int i = 0; i < 4; ++i)
                #pragma unroll
                for (int j = 0; j < 4; ++j)
                    acc[i][j] = fmaf(aa[i], bb[j], acc[i][j]);
        }
        __syncthreads();
    }
    float bias[4];
    #pragma unroll
    for (int j = 0; j < 4; ++j) {
        int n = n0 + tx * 4 + j;
        bias[j] = b0[n] + b1[n];
    }
    #pragma unroll
    for (int i = 0; i < 4; ++i) {
        int m = m0 + ty * 4 + i;
        if (m < T_SEQ) {
            #pragma unroll
            for (int j = 0; j < 4; ++j)
                C[(size_t)m * G4 + n0 + tx * 4 + j] = acc[i][j] + bias[j];
        }
    }
}

// ---------------- Ap/Bm GEMM (merged via blockIdx.z) -----------------------
__global__ __launch_bounds__(256) void ab_gemm(
    const float* __restrict__ L1, const float* __restrict__ W1,
    const float* __restrict__ b1, float* __restrict__ Ap,
    float* __restrict__ Bm)
{
    const int z = blockIdx.z;
    const int M = z ? N_SENT : T_SEQ;
    const float* B = W1 + (z ? 256 : 0);
    float* C = z ? Bm : Ap;

    __shared__ __align__(16) float As[16][68];
    __shared__ __align__(16) float Bs[16][68];
    int tid = threadIdx.x;
    int tx = tid & 15, ty = tid >> 4;
    int m0 = blockIdx.x * 64, n0 = blockIdx.y * 64;
    float acc[4][4] = {};
    int lrow = tid >> 2;
    int lk = (tid & 3) << 2;

    for (int k0 = 0; k0 < 256; k0 += 16) {
        int m = m0 + lrow;
        float4 av = make_float4(0.f, 0.f, 0.f, 0.f);
        if (m < M) av = *(const float4*)(L1 + (size_t)m * 256 + k0 + lk);
        As[lk + 0][lrow] = av.x; As[lk + 1][lrow] = av.y;
        As[lk + 2][lrow] = av.z; As[lk + 3][lrow] = av.w;
        float4 bv = *(const float4*)(B + (size_t)(n0 + lrow) * 512 + k0 + lk);
        Bs[lk + 0][lrow] = bv.x; Bs[lk + 1][lrow] = bv.y;
        Bs[lk + 2][lrow] = bv.z; Bs[lk + 3][lrow] = bv.w;
        __syncthreads();
        #pragma unroll
        for (int k = 0; k < 16; ++k) {
            float4 a4 = *(const float4*)&As[k][ty * 4];
            float4 b4 = *(const float4*)&Bs[k][tx * 4];
            float aa[4] = {a4.x, a4.y, a4.z, a4.w};
            float bb[4] = {b4.x, b4.y, b4.z, b4.w};
            #pragma unroll
            for (int i = 0; i < 4; ++i)
                #pragma unroll
                for (int j = 0; j < 4; ++j)
                    acc[i][j] = fmaf(aa[i], bb[j], acc[i][j]);
        }
        __syncthreads();
    }
    float bias[4];
    #pragma unroll
    for (int j = 0; j < 4; ++j) {
        int n = n0 + tx * 4 + j;
        bias[j] = z ? 0.f : b1[n];
    }
    #pragma unroll
    for (int i = 0; i < 4; ++i) {
        int m = m0 + ty * 4 + i;
        if (m < M) {
            #pragma unroll
            for (int j = 0; j < 4; ++j)
                C[(size_t)m * F_DIM + n0 + tx * 4 + j] = acc[i][j] + bias[j];
        }
    }
}

// ---------------- LSTM layer: BOTH directions fused on one CU --------------
// grid = 1, block = 1024 (16 waves, 4/SIMD). Waves 0-7 = forward dir,
// waves 8-15 = backward dir; each group is the proven gate-per-lane
// structure (lane finalizes one (unit,gate); DPP quad gather). The
// workgroup barrier lockstep-couples the two independent recurrences
// (both run exactly T_SEQ steps) so each group's serial chain (MFMA
// latency, exp2/rcp, LDS round-trip) hides under the other group's
// pipe work: per-SIMD MFMA occupancy ~553cy, VALU ~690cy, vs the
// ~855cy step we paid with 2 waves/SIMD. Store + hb write kept in ONE
// exec region BEFORE the barrier (round-4's after-barrier split was a
// measured regression). h->fp8 via HW v_cvt_pk_fp8_f32.
__global__ __launch_bounds__(1024)
__attribute__((amdgpu_waves_per_eu(4, 4)))
void lstm_layer(
    const float* __restrict__ pre,
    const float* __restrict__ Whh,
    float* __restrict__ L)
{
    const int t = threadIdx.x;
    const int dg = t >> 9;          // direction group: 0=fwd, 1=bwd
    const int tid = t & 511;
    const int wv = tid >> 6;
    const int l = tid & 63;
    const int g = l & 3;            // gate: 0=i 1=f 2=g 3=o
    const int v = (l >> 2) & 3;
    const int q = l >> 4;           // quad
    const int u = wv * 16 + 4 * q + v;  // unit this lane finalizes
    const int c15 = l & 15;         // MFMA column of this lane

    __shared__ __align__(16) unsigned char hb[2][2][HID]; // [dir][dbuf][unit]

    // B fragments: Bf[j] lane holds col c15, k = q*32..q*32+31 of B_j where
    // B_j column c = Whh row (c&3)*128 + wv*16 + 4*j + (c>>2), as e4m3.
    i32x8 Bf[4];
    #pragma unroll
    for (int j = 0; j < 4; ++j) {
        int row = (c15 & 3) * HID + wv * 16 + 4 * j + (c15 >> 2);
        const float* wr = Whh + ((size_t)dg * G4 + row) * HID + q * 32;
        i32x8 bv;
        #pragma unroll
        for (int w8 = 0; w8 < 8; ++w8) {
            bv[w8] = pack4_e4m3(wr[w8 * 4 + 0], wr[w8 * 4 + 1],
                                wr[w8 * 4 + 2], wr[w8 * 4 + 3]);
        }
        Bf[j] = bv;
    }

    if (t < 2 * HID) {
        hb[t >> 7][0][t & 127] = 0;
        hb[t >> 7][1][t & 127] = 0;
    }

    // unified activation constants (by this lane's gate type)
    const float Ag = (g == 2) ? 2.0f : 1.0f;
    const float Bg = (g == 2) ? (-2.0f * L2E) : (-L2E);
    const float Cg = (g == 2) ? -1.0f : 0.0f;
    const bool qb0 = (q & 1) != 0;
    const bool qb1 = (q & 2) != 0;

    // pre-activation: ONE float per lane per step, 3-deep prefetch
    const float* pp = pre + (size_t)dg * T_SEQ * G4;
    const int po = g * HID + u;
    float p0 = pp[po];            pp += G4;
    float p1v = pp[po];           pp += G4;
    float p2v = pp[po];           pp += G4;

    // rolling output pointer (g==0 lanes store h for unit u)
    float* Lrow = L + (size_t)(dg ? N_SENT : 0) * 256 + dg * HID + u;
    const ptrdiff_t ldelta = dg ? -(ptrdiff_t)256 : (ptrdiff_t)256;

    f32x4 a0 = {0.f, 0.f, 0.f, 0.f};
    f32x4 a1 = {0.f, 0.f, 0.f, 0.f};
    f32x4 a2 = {0.f, 0.f, 0.f, 0.f};
    f32x4 a3 = {0.f, 0.f, 0.f, 0.f};
    float c = 0.f;
    __syncthreads();

    #pragma unroll 4
    for (int s = 0; s < T_SEQ; ++s) {
        // A fragment: h fp8 bytes [q*32 .. q*32+31] (2 b128 broadcast reads)
        const uint4* hp = (const uint4*)&hb[dg][s & 1][q * 32];
        uint4 lo = hp[0];
        uint4 hi = hp[1];
        i32x8 Af = {(int)lo.x, (int)lo.y, (int)lo.z, (int)lo.w,
                    (int)hi.x, (int)hi.y, (int)hi.z, (int)hi.w};

        // branchless 3-deep prefetch (stray tail loads discarded, in-bounds:
        // they land inside the workspace and are never consumed)
        float p3 = pp[po];
        pp += G4;

        // only reg0 carries live C; regs 1-3 accumulate unread garbage
        a0[0] = p0; a1[0] = p0; a2[0] = p0; a3[0] = p0;
        a0 = __builtin_amdgcn_mfma_scale_f32_16x16x128_f8f6f4(
            Af, Bf[0], a0, 0, 0, 0, 0x7F7F7F7F, 0, 0x7F7F7F7F);
        a1 = __builtin_amdgcn_mfma_scale_f32_16x16x128_f8f6f4(
            Af, Bf[1], a1, 0, 0, 0, 0x7F7F7F7F, 0, 0x7F7F7F7F);
        a2 = __builtin_amdgcn_mfma_scale_f32_16x16x128_f8f6f4(
            Af, Bf[2], a2, 0, 0, 0, 0x7F7F7F7F, 0, 0x7F7F7F7F);
        a3 = __builtin_amdgcn_mfma_scale_f32_16x16x128_f8f6f4(
            Af, Bf[3], a3, 0, 0, 0, 0x7F7F7F7F, 0, 0x7F7F7F7F);

        // select this lane's MFMA (j = q), then ONE activation
        float xa = qb0 ? a1[0] : a0[0];
        float xb = qb0 ? a3[0] : a2[0];
        float x = qb1 ? xb : xa;
        float act = fmaf(Ag, RCPF(1.0f + EXP2F(Bg * x)), Cg);

        // gather the quad's 4 gates (i,f,g,o) via DPP broadcast
        float gi = quad_bcast(act, 0);
        float gf = quad_bcast(act, 1);
        float gg = quad_bcast(act, 2);
        float go = quad_bcast(act, 3);

        c = fmaf(gf, c, gi * gg);
        // h = go * tanh(c), with the post-tanh multiply folded into the fma:
        // R = 1/(1+2^-2kc); h = 2*go*R - go
        float R = RCPF(1.0f + EXP2F(-2.0f * L2E * c));
        float go2 = go + go;
        float h = fmaf(go2, R, -go);
        if (g == 0) {
            Lrow[0] = h;
            hb[dg][(s + 1) & 1][u] = f32_to_e4m3(h);
        }
        Lrow += ldelta;
        p0 = p1v; p1v = p2v; p2v = p3;
        LDS_BARRIER();
    }
}

// scores[i][j] = (i==j) ? -1e30 : b2 + sum_k w2[k]*tanh(Ap[i][k] + Bm[j][k])
__global__ __launch_bounds__(256) void scores_k(
    const float* __restrict__ Ap,   // [769][128]
    const float* __restrict__ Bm,   // [768][128]
    const float* __restrict__ w2,
    const float* __restrict__ b2,
    float* __restrict__ out)        // [769][768]
{
    __shared__ __align__(16) float Asl[32][132];
    __shared__ __align__(16) float Bsl[32][132];
    __shared__ __align__(16) float w2s[F_DIM];
    int tid = threadIdx.x;
    int i0 = blockIdx.x * 32, j0 = blockIdx.y * 32;

    for (int e = tid; e < 1024; e += 256) {
        int r = e >> 5;
        int qq = (e & 31) << 2;
        float4 av = (i0 + r < T_SEQ)
                        ? *(const float4*)(Ap + (size_t)(i0 + r) * F_DIM + qq)
                        : make_float4(0.f, 0.f, 0.f, 0.f);
        *(float4*)&Asl[r][qq] = av;
        float4 bv = *(const float4*)(Bm + (size_t)(j0 + r) * F_DIM + qq);
        *(float4*)&Bsl[r][qq] = bv;
    }
    if (tid < 32) {
        *(float4*)&w2s[tid * 4] = *(const float4*)(w2 + tid * 4);
    }
    __syncthreads();

    int tx = tid & 15, ty = tid >> 4;
    float s[2][2] = {};
    #pragma unroll 8
    for (int k4 = 0; k4 < F_DIM; k4 += 4) {
        float4 a0 = *(const float4*)&Asl[ty * 2][k4];
        float4 a1 = *(const float4*)&Asl[ty * 2 + 1][k4];
        float4 b0 = *(const float4*)&Bsl[tx * 2][k4];
        float4 b1v = *(const float4*)&Bsl[tx * 2 + 1][k4];
        float4 wv = *(const float4*)&w2s[k4];
        float aa[2][4] = {{a0.x, a0.y, a0.z, a0.w}, {a1.x, a1.y, a1.z, a1.w}};
        float bb[2][4] = {{b0.x, b0.y, b0.z, b0.w}, {b1v.x, b1v.y, b1v.z, b1v.w}};
        float ww[4] = {wv.x, wv.y, wv.z, wv.w};
        #pragma unroll
        for (int kk = 0; kk < 4; ++kk)
            #pragma unroll
            for (int ii = 0; ii < 2; ++ii)
                #pragma unroll
                for (int jj = 0; jj < 2; ++jj)
                    s[ii][jj] = fmaf(ww[kk],
                                     tanh_fast(aa[ii][kk] + bb[jj][kk]),
                                     s[ii][jj]);
    }

    float bb2 = b2[0];
    #pragma unroll
    for (int ii = 0; ii < 2; ++ii) {
        int i = i0 + ty * 2 + ii;
        if (i < T_SEQ) {
            #pragma unroll
            for (int jj = 0; jj < 2; ++jj) {
                int j = j0 + tx * 2 + jj;
                out[(size_t)i * N_SENT + j] =
                    (i == j) ? -1.0e30f : (s[ii][jj] + bb2);
            }
        }
    }
}

extern "C" void kernel_launch(void* const* d_in, const int* in_sizes, int n_in,
                              void* d_out, int out_size, void* d_ws, size_t ws_size,
                              hipStream_t stream) {
    const float* sent = (const float*)d_in[0];
    const float* root = (const float*)d_in[2];
    const float* Wih  = (const float*)d_in[3];  // (2,2,512,256)
    const float* Whh  = (const float*)d_in[4];  // (2,2,512,128)
    const float* bih  = (const float*)d_in[5];  // (2,2,512)
    const float* bhh  = (const float*)d_in[6];  // (2,2,512)
    const float* W1   = (const float*)d_in[7];  // (128,512)
    const float* b1   = (const float*)d_in[8];  // (128)
    const float* w2   = (const float*)d_in[9];  // (128)
    const float* b2   = (const float*)d_in[10]; // (1)
    float* out = (float*)d_out;
    float* ws = (float*)d_ws;

    float* pre = ws;                        // 2*769*512
    float* L0  = pre + 2 * T_SEQ * G4;      // 769*256
    float* L1  = L0 + T_SEQ * 256;          // 769*256
    float* Ap  = L1 + T_SEQ * 256;          // 769*128
    float* Bm  = Ap + T_SEQ * F_DIM;        // 768*128

    dim3 b256(256);

    pre_gemm_l0<<<dim3(13, 8, 2), b256, 0, stream>>>(sent, root, Wih, bih, bhh, pre);
    lstm_layer<<<1, 1024, 0, stream>>>(pre, Whh, L0);

    pre_gemm_l1<<<dim3(13, 8, 2), b256, 0, stream>>>(L0, Wih, bih, bhh, pre);
    lstm_layer<<<1, 1024, 0, stream>>>(pre, Whh + (size_t)2 * G4 * HID, L1);

    ab_gemm<<<dim3(13, 2, 2), b256, 0, stream>>>(L1, W1, b1, Ap, Bm);

    scores_k<<<dim3(25, 24), b256, 0, stream>>>(Ap, Bm, w2, b2, out);
}

// Round 6
// 673.081 us; speedup vs baseline: 1.3171x; 1.3171x over previous
//
#include <hip/hip_runtime.h>
#include <hip/hip_fp8.h>

#define T_SEQ 769
#define N_SENT 768
#define E_IN 256
#define HID 128
#define G4 512
#define F_DIM 128

typedef float f32x4 __attribute__((ext_vector_type(4)));
typedef int i32x8 __attribute__((ext_vector_type(8)));

#if __has_builtin(__builtin_amdgcn_rcpf)
#define RCPF(x) __builtin_amdgcn_rcpf(x)
#else
#define RCPF(x) (1.0f / (x))
#endif

#if __has_builtin(__builtin_amdgcn_exp2f)
#define EXP2F(x) __builtin_amdgcn_exp2f(x)
#else
#define EXP2F(x) __builtin_exp2f(x)
#endif

// LDS-only barrier: waits lgkmcnt(0) then s_barrier; global prefetch loads
// stay in flight (vmcnt not drained).
#define LDS_BARRIER() asm volatile("s_waitcnt lgkmcnt(0)\n\ts_barrier" ::: "memory")

#define L2E 1.4426950408889634f

__device__ __forceinline__ float tanh_fast(float x) {
    return fmaf(2.0f, RCPF(1.0f + EXP2F(-2.0f * L2E * x)), -1.0f);
}

// h -> e4m3 byte via the HW packed convert (single VALU op on gfx950).
__device__ __forceinline__ unsigned char f32_to_e4m3(float x) {
#if __has_builtin(__builtin_amdgcn_cvt_pk_fp8_f32)
    return (unsigned char)(__builtin_amdgcn_cvt_pk_fp8_f32(x, x, 0, false) & 0xFF);
#else
    __hip_fp8_e4m3 q(x);
    return (unsigned char)q.__x;
#endif
}

// pack 4 floats -> 4 e4m3 bytes in one dword (2 HW instructions)
__device__ __forceinline__ int pack4_e4m3(float w0, float w1, float w2, float w3) {
#if __has_builtin(__builtin_amdgcn_cvt_pk_fp8_f32)
    int r = __builtin_amdgcn_cvt_pk_fp8_f32(w0, w1, 0, false);   // bits 15:0
    return __builtin_amdgcn_cvt_pk_fp8_f32(w2, w3, r, true);     // bits 31:16
#else
    unsigned x = 0;
    __hip_fp8_e4m3 q0(w0), q1(w1), q2(w2), q3(w3);
    x |= (unsigned)q0.__x;
    x |= (unsigned)q1.__x << 8;
    x |= (unsigned)q2.__x << 16;
    x |= (unsigned)q3.__x << 24;
    return (int)x;
#endif
}

// quad-lane broadcast via DPP (lanes [4k..4k+3] all get lane 4k+sel)
__device__ __forceinline__ float quad_bcast(float x, const int sel) {
#if __has_builtin(__builtin_amdgcn_mov_dpp)
    // quad_perm: all four 2-bit selects = sel -> 0x00 / 0x55 / 0xAA / 0xFF
    int ctrl = sel * 0x55;
    int r;
    switch (ctrl) {
        case 0x00: r = __builtin_amdgcn_mov_dpp(__float_as_int(x), 0x00, 0xF, 0xF, true); break;
        case 0x55: r = __builtin_amdgcn_mov_dpp(__float_as_int(x), 0x55, 0xF, 0xF, true); break;
        case 0xAA: r = __builtin_amdgcn_mov_dpp(__float_as_int(x), 0xAA, 0xF, 0xF, true); break;
        default:   r = __builtin_amdgcn_mov_dpp(__float_as_int(x), 0xFF, 0xF, 0xF, true); break;
    }
    return __int_as_float(r);
#else
    int lane = __lane_id();
    return __shfl(x, (lane & ~3) + sel, 64);
#endif
}

// ---------------- pre-GEMM, layer 0 (x built inline from sent/root) --------
__global__ __launch_bounds__(256) void pre_gemm_l0(
    const float* __restrict__ sent, const float* __restrict__ root,
    const float* __restrict__ Wih, const float* __restrict__ bih,
    const float* __restrict__ bhh, float* __restrict__ pre)
{
    const int d = blockIdx.z;
    const float* B = Wih + (size_t)d * G4 * E_IN;
    const float* b0 = bih + (size_t)d * G4;
    const float* b1 = bhh + (size_t)d * G4;
    float* C = pre + (size_t)d * T_SEQ * G4;

    __shared__ __align__(16) float As[16][68];
    __shared__ __align__(16) float Bs[16][68];
    int tid = threadIdx.x;
    int tx = tid & 15, ty = tid >> 4;
    int m0 = blockIdx.x * 64, n0 = blockIdx.y * 64;
    float acc[4][4] = {};
    int lrow = tid >> 2;
    int lk = (tid & 3) << 2;

    for (int k0 = 0; k0 < E_IN; k0 += 16) {
        int m = m0 + lrow;
        float4 av = make_float4(0.f, 0.f, 0.f, 0.f);
        if (m < T_SEQ) {
            int ar = d ? (N_SENT - m) : m;
            av = (ar < N_SENT)
                     ? *(const float4*)(sent + (size_t)ar * E_IN + k0 + lk)
                     : *(const float4*)(root + k0 + lk);
        }
        As[lk + 0][lrow] = av.x; As[lk + 1][lrow] = av.y;
        As[lk + 2][lrow] = av.z; As[lk + 3][lrow] = av.w;
        float4 bv = *(const float4*)(B + (size_t)(n0 + lrow) * E_IN + k0 + lk);
        Bs[lk + 0][lrow] = bv.x; Bs[lk + 1][lrow] = bv.y;
        Bs[lk + 2][lrow] = bv.z; Bs[lk + 3][lrow] = bv.w;
        __syncthreads();
        #pragma unroll
        for (int k = 0; k < 16; ++k) {
            float4 a4 = *(const float4*)&As[k][ty * 4];
            float4 b4 = *(const float4*)&Bs[k][tx * 4];
            float aa[4] = {a4.x, a4.y, a4.z, a4.w};
            float bb[4] = {b4.x, b4.y, b4.z, b4.w};
            #pragma unroll
            for (int i = 0; i < 4; ++i)
                #pragma unroll
                for (int j = 0; j < 4; ++j)
                    acc[i][j] = fmaf(aa[i], bb[j], acc[i][j]);
        }
        __syncthreads();
    }
    float bias[4];
    #pragma unroll
    for (int j = 0; j < 4; ++j) {
        int n = n0 + tx * 4 + j;
        bias[j] = b0[n] + b1[n];
    }
    #pragma unroll
    for (int i = 0; i < 4; ++i) {
        int m = m0 + ty * 4 + i;
        if (m < T_SEQ) {
            #pragma unroll
            for (int j = 0; j < 4; ++j)
                C[(size_t)m * G4 + n0 + tx * 4 + j] = acc[i][j] + bias[j];
        }
    }
}

// ---------------- pre-GEMM, layer 1 ---------------------------------------
__global__ __launch_bounds__(256) void pre_gemm_l1(
    const float* __restrict__ L0,
    const float* __restrict__ Wih, const float* __restrict__ bih,
    const float* __restrict__ bhh, float* __restrict__ pre)
{
    const int d = blockIdx.z;
    const float* B = Wih + (size_t)(2 + d) * G4 * E_IN;
    const float* b0 = bih + (size_t)(2 + d) * G4;
    const float* b1 = bhh + (size_t)(2 + d) * G4;
    float* C = pre + (size_t)d * T_SEQ * G4;

    __shared__ __align__(16) float As[16][68];
    __shared__ __align__(16) float Bs[16][68];
    int tid = threadIdx.x;
    int tx = tid & 15, ty = tid >> 4;
    int m0 = blockIdx.x * 64, n0 = blockIdx.y * 64;
    float acc[4][4] = {};
    int lrow = tid >> 2;
    int lk = (tid & 3) << 2;

    for (int k0 = 0; k0 < 256; k0 += 16) {
        int m = m0 + lrow;
        float4 av = make_float4(0.f, 0.f, 0.f, 0.f);
        if (m < T_SEQ) {
            int ar = d ? (N_SENT - m) : m;
            av = *(const float4*)(L0 + (size_t)ar * 256 + k0 + lk);
        }
        As[lk + 0][lrow] = av.x; As[lk + 1][lrow] = av.y;
        As[lk + 2][lrow] = av.z; As[lk + 3][lrow] = av.w;
        float4 bv = *(const float4*)(B + (size_t)(n0 + lrow) * 256 + k0 + lk);
        Bs[lk + 0][lrow] = bv.x; Bs[lk + 1][lrow] = bv.y;
        Bs[lk + 2][lrow] = bv.z; Bs[lk + 3][lrow] = bv.w;
        __syncthreads();
        #pragma unroll
        for (int k = 0; k < 16; ++k) {
            float4 a4 = *(const float4*)&As[k][ty * 4];
            float4 b4 = *(const float4*)&Bs[k][tx * 4];
            float aa[4] = {a4.x, a4.y, a4.z, a4.w};
            float bb[4] = {b4.x, b4.y, b4.z, b4.w};
            #pragma unroll
            for (int i = 0; i < 4; ++i)
                #pragma unroll
                for (int j = 0; j < 4; ++j)
                    acc[i][j] = fmaf(aa[i], bb[j], acc[i][j]);
        }
        __syncthreads();
    }
    float bias[4];
    #pragma unroll
    for (int j = 0; j < 4; ++j) {
        int n = n0 + tx * 4 + j;
        bias[j] = b0[n] + b1[n];
    }
    #pragma unroll
    for (int i = 0; i < 4; ++i) {
        int m = m0 + ty * 4 + i;
        if (m < T_SEQ) {
            #pragma unroll
            for (int j = 0; j < 4; ++j)
                C[(size_t)m * G4 + n0 + tx * 4 + j] = acc[i][j] + bias[j];
        }
    }
}

// ---------------- Ap/Bm GEMM (merged via blockIdx.z) -----------------------
__global__ __launch_bounds__(256) void ab_gemm(
    const float* __restrict__ L1, const float* __restrict__ W1,
    const float* __restrict__ b1, float* __restrict__ Ap,
    float* __restrict__ Bm)
{
    const int z = blockIdx.z;
    const int M = z ? N_SENT : T_SEQ;
    const float* B = W1 + (z ? 256 : 0);
    float* C = z ? Bm : Ap;

    __shared__ __align__(16) float As[16][68];
    __shared__ __align__(16) float Bs[16][68];
    int tid = threadIdx.x;
    int tx = tid & 15, ty = tid >> 4;
    int m0 = blockIdx.x * 64, n0 = blockIdx.y * 64;
    float acc[4][4] = {};
    int lrow = tid >> 2;
    int lk = (tid & 3) << 2;

    for (int k0 = 0; k0 < 256; k0 += 16) {
        int m = m0 + lrow;
        float4 av = make_float4(0.f, 0.f, 0.f, 0.f);
        if (m < M) av = *(const float4*)(L1 + (size_t)m * 256 + k0 + lk);
        As[lk + 0][lrow] = av.x; As[lk + 1][lrow] = av.y;
        As[lk + 2][lrow] = av.z; As[lk + 3][lrow] = av.w;
        float4 bv = *(const float4*)(B + (size_t)(n0 + lrow) * 512 + k0 + lk);
        Bs[lk + 0][lrow] = bv.x; Bs[lk + 1][lrow] = bv.y;
        Bs[lk + 2][lrow] = bv.z; Bs[lk + 3][lrow] = bv.w;
        __syncthreads();
        #pragma unroll
        for (int k = 0; k < 16; ++k) {
            float4 a4 = *(const float4*)&As[k][ty * 4];
            float4 b4 = *(const float4*)&Bs[k][tx * 4];
            float aa[4] = {a4.x, a4.y, a4.z, a4.w};
            float bb[4] = {b4.x, b4.y, b4.z, b4.w};
            #pragma unroll
            for (int i = 0; i < 4; ++i)
                #pragma unroll
                for (int j = 0; j < 4; ++j)
                    acc[i][j] = fmaf(aa[i], bb[j], acc[i][j]);
        }
        __syncthreads();
    }
    float bias[4];
    #pragma unroll
    for (int j = 0; j < 4; ++j) {
        int n = n0 + tx * 4 + j;
        bias[j] = z ? 0.f : b1[n];
    }
    #pragma unroll
    for (int i = 0; i < 4; ++i) {
        int m = m0 + ty * 4 + i;
        if (m < M) {
            #pragma unroll
            for (int j = 0; j < 4; ++j)
                C[(size_t)m * F_DIM + n0 + tx * 4 + j] = acc[i][j] + bias[j];
        }
    }
}

// ---------------- LSTM layer: gate-per-lane K=128 fp8 MFMA -----------------
// grid = 2 (dir), block = 512 (8 waves, 2/SIMD) -- the verified-best layout
// (one direction per CU; round-5's 16-wave fusion doubled the per-SIMD MFMA
// queue on the critical path and regressed 274->373us).
// Each LANE finalizes one (unit, gate) pair; gates gathered across the
// 4-lane quad via DPP. This revision: Af loaded as ONE i32x8 LDS read
// (2x ds_read_b128 directly into the MFMA operand tuple -- kills the
// uint4->i32x8 marshalling movs on the chain); HW v_cvt_pk_fp8 for h->e4m3
// (verified VALU cut in round 4); store + hb write in ONE exec region
// BEFORE the barrier (round-4's after-barrier split regressed).
__global__ __launch_bounds__(512)
__attribute__((amdgpu_waves_per_eu(2, 2)))
void lstm_layer(
    const float* __restrict__ pre,
    const float* __restrict__ Whh,
    float* __restrict__ L)
{
    const int d = blockIdx.x;
    const int t = threadIdx.x;
    const int wv = t >> 6;
    const int l = t & 63;
    const int g = l & 3;            // gate: 0=i 1=f 2=g 3=o
    const int v = (l >> 2) & 3;
    const int q = l >> 4;           // quad
    const int u = wv * 16 + 4 * q + v;  // unit this lane finalizes
    const int c15 = l & 15;         // MFMA column of this lane

    __shared__ __align__(16) unsigned char hb[2][HID];  // h as fp8 e4m3, dbuf

    // B fragments: Bf[j] lane holds col c15, k = q*32..q*32+31 of B_j where
    // B_j column c = Whh row (c&3)*128 + wv*16 + 4*j + (c>>2), as e4m3.
    i32x8 Bf[4];
    #pragma unroll
    for (int j = 0; j < 4; ++j) {
        int row = (c15 & 3) * HID + wv * 16 + 4 * j + (c15 >> 2);
        const float* wr = Whh + ((size_t)d * G4 + row) * HID + q * 32;
        i32x8 bv;
        #pragma unroll
        for (int w8 = 0; w8 < 8; ++w8) {
            bv[w8] = pack4_e4m3(wr[w8 * 4 + 0], wr[w8 * 4 + 1],
                                wr[w8 * 4 + 2], wr[w8 * 4 + 3]);
        }
        Bf[j] = bv;
    }

    if (t < HID) { hb[0][t] = 0; hb[1][t] = 0; }

    // unified activation constants (by this lane's gate type)
    const float Ag = (g == 2) ? 2.0f : 1.0f;
    const float Bg = (g == 2) ? (-2.0f * L2E) : (-L2E);
    const float Cg = (g == 2) ? -1.0f : 0.0f;
    const bool qb0 = (q & 1) != 0;
    const bool qb1 = (q & 2) != 0;

    // pre-activation: ONE float per lane per step, 3-deep prefetch
    const float* pp = pre + (size_t)d * T_SEQ * G4;
    const int po = g * HID + u;
    float p0 = pp[po];            pp += G4;
    float p1v = pp[po];           pp += G4;
    float p2v = pp[po];           pp += G4;

    // rolling output pointer (g==0 lanes store h for unit u)
    float* Lrow = L + (size_t)(d ? N_SENT : 0) * 256 + d * HID + u;
    const ptrdiff_t ldelta = d ? -(ptrdiff_t)256 : (ptrdiff_t)256;

    f32x4 a0 = {0.f, 0.f, 0.f, 0.f};
    f32x4 a1 = {0.f, 0.f, 0.f, 0.f};
    f32x4 a2 = {0.f, 0.f, 0.f, 0.f};
    f32x4 a3 = {0.f, 0.f, 0.f, 0.f};
    float c = 0.f;
    __syncthreads();

    #pragma unroll 4
    for (int s = 0; s < T_SEQ; ++s) {
        // A fragment: h fp8 bytes [q*32 .. q*32+31] as one 32B vector load
        // (2x ds_read_b128 straight into the 8-reg MFMA operand, no movs)
        i32x8 Af = *(const i32x8*)&hb[s & 1][q * 32];

        // branchless 3-deep prefetch (stray tail loads discarded, in-bounds)
        float p3 = pp[po];
        pp += G4;

        // only reg0 carries live C; regs 1-3 accumulate unread garbage
        a0[0] = p0; a1[0] = p0; a2[0] = p0; a3[0] = p0;
        a0 = __builtin_amdgcn_mfma_scale_f32_16x16x128_f8f6f4(
            Af, Bf[0], a0, 0, 0, 0, 0x7F7F7F7F, 0, 0x7F7F7F7F);
        a1 = __builtin_amdgcn_mfma_scale_f32_16x16x128_f8f6f4(
            Af, Bf[1], a1, 0, 0, 0, 0x7F7F7F7F, 0, 0x7F7F7F7F);
        a2 = __builtin_amdgcn_mfma_scale_f32_16x16x128_f8f6f4(
            Af, Bf[2], a2, 0, 0, 0, 0x7F7F7F7F, 0, 0x7F7F7F7F);
        a3 = __builtin_amdgcn_mfma_scale_f32_16x16x128_f8f6f4(
            Af, Bf[3], a3, 0, 0, 0, 0x7F7F7F7F, 0, 0x7F7F7F7F);

        // select this lane's MFMA (j = q), then ONE activation
        float xa = qb0 ? a1[0] : a0[0];
        float xb = qb0 ? a3[0] : a2[0];
        float x = qb1 ? xb : xa;
        float act = fmaf(Ag, RCPF(1.0f + EXP2F(Bg * x)), Cg);

        // gather the quad's 4 gates (i,f,g,o) via DPP broadcast
        float gi = quad_bcast(act, 0);
        float gf = quad_bcast(act, 1);
        float gg = quad_bcast(act, 2);
        float go = quad_bcast(act, 3);

        c = fmaf(gf, c, gi * gg);
        // h = go * tanh(c) with the post-tanh multiply folded:
        // R = 1/(1+2^-2kc); h = 2*go*R - go
        float R = RCPF(1.0f + EXP2F(-2.0f * L2E * c));
        float go2 = go + go;
        float h = fmaf(go2, R, -go);
        if (g == 0) {
            Lrow[0] = h;
            hb[(s + 1) & 1][u] = f32_to_e4m3(h);
        }
        Lrow += ldelta;
        p0 = p1v; p1v = p2v; p2v = p3;
        LDS_BARRIER();
    }
}

// scores[i][j] = (i==j) ? -1e30 : b2 + sum_k w2[k]*tanh(Ap[i][k] + Bm[j][k])
__global__ __launch_bounds__(256) void scores_k(
    const float* __restrict__ Ap,   // [769][128]
    const float* __restrict__ Bm,   // [768][128]
    const float* __restrict__ w2,
    const float* __restrict__ b2,
    float* __restrict__ out)        // [769][768]
{
    __shared__ __align__(16) float Asl[32][132];
    __shared__ __align__(16) float Bsl[32][132];
    __shared__ __align__(16) float w2s[F_DIM];
    int tid = threadIdx.x;
    int i0 = blockIdx.x * 32, j0 = blockIdx.y * 32;

    for (int e = tid; e < 1024; e += 256) {
        int r = e >> 5;
        int qq = (e & 31) << 2;
        float4 av = (i0 + r < T_SEQ)
                        ? *(const float4*)(Ap + (size_t)(i0 + r) * F_DIM + qq)
                        : make_float4(0.f, 0.f, 0.f, 0.f);
        *(float4*)&Asl[r][qq] = av;
        float4 bv = *(const float4*)(Bm + (size_t)(j0 + r) * F_DIM + qq);
        *(float4*)&Bsl[r][qq] = bv;
    }
    if (tid < 32) {
        *(float4*)&w2s[tid * 4] = *(const float4*)(w2 + tid * 4);
    }
    __syncthreads();

    int tx = tid & 15, ty = tid >> 4;
    float s[2][2] = {};
    #pragma unroll 8
    for (int k4 = 0; k4 < F_DIM; k4 += 4) {
        float4 a0 = *(const float4*)&Asl[ty * 2][k4];
        float4 a1 = *(const float4*)&Asl[ty * 2 + 1][k4];
        float4 b0 = *(const float4*)&Bsl[tx * 2][k4];
        float4 b1v = *(const float4*)&Bsl[tx * 2 + 1][k4];
        float4 wv = *(const float4*)&w2s[k4];
        float aa[2][4] = {{a0.x, a0.y, a0.z, a0.w}, {a1.x, a1.y, a1.z, a1.w}};
        float bb[2][4] = {{b0.x, b0.y, b0.z, b0.w}, {b1v.x, b1v.y, b1v.z, b1v.w}};
        float ww[4] = {wv.x, wv.y, wv.z, wv.w};
        #pragma unroll
        for (int kk = 0; kk < 4; ++kk)
            #pragma unroll
            for (int ii = 0; ii < 2; ++ii)
                #pragma unroll
                for (int jj = 0; jj < 2; ++jj)
                    s[ii][jj] = fmaf(ww[kk],
                                     tanh_fast(aa[ii][kk] + bb[jj][kk]),
                                     s[ii][jj]);
    }

    float bb2 = b2[0];
    #pragma unroll
    for (int ii = 0; ii < 2; ++ii) {
        int i = i0 + ty * 2 + ii;
        if (i < T_SEQ) {
            #pragma unroll
            for (int jj = 0; jj < 2; ++jj) {
                int j = j0 + tx * 2 + jj;
                out[(size_t)i * N_SENT + j] =
                    (i == j) ? -1.0e30f : (s[ii][jj] + bb2);
            }
        }
    }
}

extern "C" void kernel_launch(void* const* d_in, const int* in_sizes, int n_in,
                              void* d_out, int out_size, void* d_ws, size_t ws_size,
                              hipStream_t stream) {
    const float* sent = (const float*)d_in[0];
    const float* root = (const float*)d_in[2];
    const float* Wih  = (const float*)d_in[3];  // (2,2,512,256)
    const float* Whh  = (const float*)d_in[4];  // (2,2,512,128)
    const float* bih  = (const float*)d_in[5];  // (2,2,512)
    const float* bhh  = (const float*)d_in[6];  // (2,2,512)
    const float* W1   = (const float*)d_in[7];  // (128,512)
    const float* b1   = (const float*)d_in[8];  // (128)
    const float* w2   = (const float*)d_in[9];  // (128)
    const float* b2   = (const float*)d_in[10]; // (1)
    float* out = (float*)d_out;
    float* ws = (float*)d_ws;

    float* pre = ws;                        // 2*769*512
    float* L0  = pre + 2 * T_SEQ * G4;      // 769*256
    float* L1  = L0 + T_SEQ * 256;          // 769*256
    float* Ap  = L1 + T_SEQ * 256;          // 769*128
    float* Bm  = Ap + T_SEQ * F_DIM;        // 768*128

    dim3 b256(256);

    pre_gemm_l0<<<dim3(13, 8, 2), b256, 0, stream>>>(sent, root, Wih, bih, bhh, pre);
    lstm_layer<<<2, 512, 0, stream>>>(pre, Whh, L0);

    pre_gemm_l1<<<dim3(13, 8, 2), b256, 0, stream>>>(L0, Wih, bih, bhh, pre);
    lstm_layer<<<2, 512, 0, stream>>>(pre, Whh + (size_t)2 * G4 * HID, L1);

    ab_gemm<<<dim3(13, 2, 2), b256, 0, stream>>>(L1, W1, b1, Ap, Bm);

    scores_k<<<dim3(25, 24), b256, 0, stream>>>(Ap, Bm, w2, b2, out);
}